// Round 1
// baseline (513.855 us; speedup 1.0000x reference)
//
#include <hip/hip_runtime.h>
#include <hip/hip_bf16.h>

#define B_ 32
#define N_ 2048
#define D_ 16
#define J_ 64
#define C_ 32
#define NCHUNK 32
#define ICHUNK 64          // N_/NCHUNK
#define IPW    16          // ICHUNK/4 waves

typedef __attribute__((ext_vector_type(8)))  short short8;
typedef __attribute__((ext_vector_type(4)))  short s16x4;
typedef __attribute__((ext_vector_type(16))) float f32x16;
typedef __attribute__((ext_vector_type(4)))  float f32x4;
typedef __attribute__((ext_vector_type(16))) int   i32x16;
typedef __attribute__((ext_vector_type(2)))  long  longx2;

using bf16_t = __hip_bfloat16;

// ---------------------------------------------------------------------------
// Prep: u (B,N,D) fp32 -> ut (N,B,D) bf16 (fallback path) + uq (N,B,D) int8
// with per-row scale su[i,b] = rowmax/127. One thread per (i,b) row of 16.
// Reads are 64B-contiguous per lane (full cache lines), writes coalesced.
// ---------------------------------------------------------------------------
__global__ __launch_bounds__(256) void prep_u_kernel(const float* __restrict__ x,
                                                     bf16_t* __restrict__ ut,
                                                     signed char* __restrict__ uq,
                                                     float* __restrict__ su) {
  int t = blockIdx.x * 256 + threadIdx.x;   // t = i*32 + b
  int b = t & 31;
  int i = t >> 5;
  const float* xp = x + (size_t)(b * N_ + i) * D_;
  float v[16];
  *(f32x4*)(v)      = *(const f32x4*)(xp);
  *(f32x4*)(v + 4)  = *(const f32x4*)(xp + 4);
  *(f32x4*)(v + 8)  = *(const f32x4*)(xp + 8);
  *(f32x4*)(v + 12) = *(const f32x4*)(xp + 12);

  float m = 0.f;
#pragma unroll
  for (int k = 0; k < 16; ++k) m = fmaxf(m, fabsf(v[k]));
  m = fmaxf(m, 1e-20f);
  float inv = 127.0f / m;
  union { longx2 l2; signed char c[16]; } pk;
#pragma unroll
  for (int k = 0; k < 16; ++k) pk.c[k] = (signed char)__float2int_rn(v[k] * inv);
  *(longx2*)(uq + (size_t)t * D_) = pk.l2;
  su[t] = m * (1.0f / 127.0f);

  union { short8 s; bf16_t h[8]; } o0, o1;
#pragma unroll
  for (int k = 0; k < 8; ++k) { o0.h[k] = __float2bfloat16(v[k]); o1.h[k] = __float2bfloat16(v[8 + k]); }
  *(short8*)(ut + (size_t)t * D_)     = o0.s;
  *(short8*)(ut + (size_t)t * D_ + 8) = o1.s;
}

// ---------------------------------------------------------------------------
// Routing pass. One block = (j, i-chunk of 64), 4 waves, 1 wave = 16 i's.
// SWAPPED OPERANDS: mfma(wfrag, ufrag) -> acc[m=c][n=b]:
//   col b = lane&31, row c = (r&3) + 4*(lane>>5) + 8*(r>>2)
// A/B frags share the (free,k) lane layout, so any consistent HW k-mapping
// pairs W[c,d] with u[b,d] correctly (same invariance as the bf16 version).
// int8 dequant: u_hat = (sw[i,j]*su[i,b]) * acc; b=lc so s is a per-lane
// scalar and folds into the logit dot (ph*=s) and S update (es=e*s).
// MODE 0: fp32 W in, quantize+store int8 W + per-tile scale, uniform weights
// MODE 1: int8 W in, V-based logits (iters 1-4)
// MODE 2: fp32 W in, uniform, bf16 mfma, no store (fallback iter 0)
// MODE 3: fp32 W in, V-based logits, bf16 mfma, no store (fallback)
// ---------------------------------------------------------------------------
template<int MODE>
__global__ __launch_bounds__(256) void pass_kernel(
    const float*        __restrict__ Wf,
    const signed char*  __restrict__ Wq,
    signed char*        __restrict__ Wqo,
    float*              __restrict__ SWo,
    const float*        __restrict__ SW,
    const signed char*  __restrict__ uq,
    const float*        __restrict__ su,
    const bf16_t*       __restrict__ ut,
    const float*        __restrict__ V,
    float*              __restrict__ PS,
    float*              __restrict__ PZ)
{
  constexpr bool UNIFORM = (MODE == 0 || MODE == 2);
  constexpr bool INT8    = (MODE == 0 || MODE == 1);

  const int tid  = threadIdx.x;
  const int w    = tid >> 6;
  const int lane = tid & 63;
  const int half = lane >> 5;
  const int lc   = lane & 31;          // = b ; also A-frag m / B-frag n

  const int j  = blockIdx.x / NCHUNK;
  const int ch = blockIdx.x % NCHUNK;

  // C/D row (= c) per accumulator reg (measured m74/m101; dtype-independent)
  int crow[16];
#pragma unroll
  for (int r = 0; r < 16; ++r) crow[r] = (r & 3) + 4 * half + 8 * (r >> 2);

  float Vreg[16];
  if (!UNIFORM) {
#pragma unroll
    for (int r = 0; r < 16; ++r) Vreg[r] = V[(lc * J_ + j) * C_ + crow[r]];
  }

  float S[16];
#pragma unroll
  for (int r = 0; r < 16; ++r) S[r] = 0.f;
  float zacc = 0.f;

  const int ibase = ch * ICHUNK + w * IPW;
  const int frag_off = lc * D_ + half * 8;   // element (=byte for i8) offset in 32x16 tile

  if constexpr (INT8) {
    const i32x16 zi = {0,0,0,0,0,0,0,0,0,0,0,0,0,0,0,0};
    for (int t = 0; t < IPW; ++t) {
      const int i = ibase + t;
      long ul = *(const long*)(uq + (size_t)i * (B_ * D_) + frag_off);
      const size_t tile = ((size_t)i * J_ + j) * (C_ * D_);
      long wl;
      float sw_i;
      if constexpr (MODE == 0) {
        const float* wp = Wf + tile + frag_off;
        f32x4 w0 = *(const f32x4*)(wp);
        f32x4 w1 = *(const f32x4*)(wp + 4);
        float wv[8] = {w0.x, w0.y, w0.z, w0.w, w1.x, w1.y, w1.z, w1.w};
        float m = 0.f;
#pragma unroll
        for (int k = 0; k < 8; ++k) m = fmaxf(m, fabsf(wv[k]));
        // tile absmax across the full wave (tile is 512 values over 64 lanes)
        m = fmaxf(m, __shfl_xor(m, 1));
        m = fmaxf(m, __shfl_xor(m, 2));
        m = fmaxf(m, __shfl_xor(m, 4));
        m = fmaxf(m, __shfl_xor(m, 8));
        m = fmaxf(m, __shfl_xor(m, 16));
        m = fmaxf(m, __shfl_xor(m, 32));
        m = fmaxf(m, 1e-20f);
        float qs = 127.0f / m;
        union { long l; signed char c[8]; } pk;
#pragma unroll
        for (int k = 0; k < 8; ++k) pk.c[k] = (signed char)__float2int_rn(wv[k] * qs);
        wl = pk.l;
        sw_i = m * (1.0f / 127.0f);
        *(long*)(Wqo + tile + frag_off) = wl;
        if (lane == 0) SWo[(size_t)i * J_ + j] = sw_i;
      } else {
        wl = *(const long*)(Wq + tile + frag_off);
        sw_i = SW[(size_t)i * J_ + j];        // wave-uniform, L2-hot
      }
      const float s = sw_i * su[i * B_ + lc];  // per-lane dequant scalar

      i32x16 iacc = __builtin_amdgcn_mfma_i32_32x32x16_i8(wl, ul, zi, 0, 0, 0);

      if constexpr (UNIFORM) {
#pragma unroll
        for (int r = 0; r < 16; ++r) S[r] = fmaf(s, (float)iacc[r], S[r]);
      } else {
        float af[16];
        float ph = 0.f;
#pragma unroll
        for (int r = 0; r < 16; ++r) { af[r] = (float)iacc[r]; ph = fmaf(Vreg[r], af[r], ph); }
        ph *= s;                             // dequant the half-dot
        ph += __shfl_xor(ph, 32);            // combine the two half-row sets
        float e = __expf(ph);                // logits are O(0.5); max-free safe
        zacc += e;
        float es = e * s;
#pragma unroll
        for (int r = 0; r < 16; ++r) S[r] = fmaf(es, af[r], S[r]);
      }
    }
  } else {
    const f32x16 zeroacc = {0,0,0,0,0,0,0,0,0,0,0,0,0,0,0,0};
    for (int t = 0; t < IPW; ++t) {
      const int i = ibase + t;
      short8 ufrag = *(const short8*)(ut + (size_t)i * (B_ * D_) + frag_off);
      const size_t tile = ((size_t)i * J_ + j) * (C_ * D_);
      const float* wp = Wf + tile + frag_off;
      f32x4 w0 = *(const f32x4*)(wp);
      f32x4 w1 = *(const f32x4*)(wp + 4);
      union { short8 v; bf16_t h[8]; } cv;
      cv.h[0] = __float2bfloat16(w0.x);
      cv.h[1] = __float2bfloat16(w0.y);
      cv.h[2] = __float2bfloat16(w0.z);
      cv.h[3] = __float2bfloat16(w0.w);
      cv.h[4] = __float2bfloat16(w1.x);
      cv.h[5] = __float2bfloat16(w1.y);
      cv.h[6] = __float2bfloat16(w1.z);
      cv.h[7] = __float2bfloat16(w1.w);
      short8 wfrag = cv.v;

      f32x16 acc = __builtin_amdgcn_mfma_f32_32x32x16_bf16(wfrag, ufrag, zeroacc, 0, 0, 0);

      if constexpr (UNIFORM) {
#pragma unroll
        for (int r = 0; r < 16; ++r) S[r] += acc[r];
      } else {
        float ph = 0.f;
#pragma unroll
        for (int r = 0; r < 16; ++r) ph = fmaf(Vreg[r], acc[r], ph);
        ph += __shfl_xor(ph, 32);
        float e = __expf(ph);
        zacc += e;
#pragma unroll
        for (int r = 0; r < 16; ++r) S[r] = fmaf(e, acc[r], S[r]);
      }
    }
  }

  // Epilogue: transpose [c][b] -> [b][c] through padded LDS (stride 33:
  // bank = (lc + crow) % 32, conflict-free), then coalesced PS writes.
  __shared__ float S_lds[4 * 32 * 33];
  __shared__ float Z_lds[4 * 32];
#pragma unroll
  for (int r = 0; r < 16; ++r)
    S_lds[w * 1056 + lc * 33 + crow[r]] = S[r];
  if (!half)
    Z_lds[w * 32 + lc] = UNIFORM ? (float)IPW : zacc;
  __syncthreads();

  const size_t pbase = (size_t)blockIdx.x * 1024;
  for (int e = tid; e < 1024; e += 256) {
    int b = e >> 5, c = e & 31;
    PS[pbase + e] = S_lds[b * 33 + c] + S_lds[1056 + b * 33 + c] +
                    S_lds[2112 + b * 33 + c] + S_lds[3168 + b * 33 + c];
  }
  if (tid < 32)
    PZ[(size_t)blockIdx.x * 32 + tid] =
        Z_lds[tid] + Z_lds[32 + tid] + Z_lds[64 + tid] + Z_lds[96 + tid];
}

// ---------------------------------------------------------------------------
// Combine chunks -> s, squash -> v, V += v, final iter writes output.
// ---------------------------------------------------------------------------
__global__ __launch_bounds__(256) void combine_kernel(
    const float* __restrict__ PS, const float* __restrict__ PZ,
    float* __restrict__ V, float* __restrict__ out, int first, int last)
{
  int t  = blockIdx.x * 256 + threadIdx.x;  // ((b*J + j)*32 + c)
  int c  = t & 31;
  int bj = t >> 5;
  int b  = bj >> 6;
  int j  = bj & 63;
  float s = 0.f, zz = 0.f;
#pragma unroll
  for (int ch = 0; ch < NCHUNK; ++ch) {
    s  += PS[(size_t)(j * NCHUNK + ch) * 1024 + b * 32 + c];
    zz += PZ[(j * NCHUNK + ch) * 32 + b];
  }
  float sv = s / zz + 1e-7f;                // squash adds eps per-component
  float n = sv * sv;
  n += __shfl_xor(n, 1);
  n += __shfl_xor(n, 2);
  n += __shfl_xor(n, 4);
  n += __shfl_xor(n, 8);
  n += __shfl_xor(n, 16);
  float f = n / ((1.f + n) * sqrtf(n));
  float v = sv * f;
  float Vn = first ? v : (V[t] + v);
  V[t] = Vn;
  if (last) out[t] = v;
}

extern "C" void kernel_launch(void* const* d_in, const int* in_sizes, int n_in,
                              void* d_out, int out_size, void* d_ws, size_t ws_size,
                              hipStream_t stream)
{
  const float* x  = (const float*)d_in[0];
  const float* Wf = (const float*)d_in[1];
  float* out = (float*)d_out;
  char* ws = (char*)d_ws;

  const size_t SZ_WQ = (size_t)N_ * J_ * C_ * D_;          // 64 MB int8 W cache
  const size_t SZ_SW = (size_t)N_ * J_ * 4;                // 512 KB W tile scales
  const size_t SZ_UQ = (size_t)N_ * B_ * D_;               // 1 MB int8 u
  const size_t SZ_SU = (size_t)N_ * B_ * 4;                // 256 KB u row scales
  const size_t SZ_UT = (size_t)N_ * B_ * D_ * 2;           // 2 MB bf16 u (fallback)
  const size_t SZ_V  = (size_t)B_ * J_ * C_ * 4;           // 256 KB
  const size_t SZ_PS = (size_t)J_ * NCHUNK * B_ * C_ * 4;  // 8 MB
  const size_t SZ_PZ = (size_t)J_ * NCHUNK * B_ * 4;       // 256 KB

  const bool big = ws_size >= SZ_WQ + SZ_SW + SZ_UQ + SZ_SU + SZ_UT + SZ_V + SZ_PS + SZ_PZ;
  char* p = ws;
  signed char* Wq = nullptr;
  float* SWp = nullptr;
  if (big) {
    Wq  = (signed char*)p; p += SZ_WQ;
    SWp = (float*)p;       p += SZ_SW;
  }
  signed char* uq = (signed char*)p; p += SZ_UQ;
  float* su = (float*)p;             p += SZ_SU;
  bf16_t* ut = (bf16_t*)p;           p += SZ_UT;
  float*  V  = (float*)p;            p += SZ_V;
  float*  PS = (float*)p;            p += SZ_PS;
  float*  PZ = (float*)p;

  prep_u_kernel<<<dim3((N_ * B_) / 256), dim3(256), 0, stream>>>(x, ut, uq, su);

  dim3 gA(J_ * NCHUNK), blk(256), gB((B_ * J_ * C_) / 256);
  if (big) {
    pass_kernel<0><<<gA, blk, 0, stream>>>(Wf, nullptr, Wq, SWp, nullptr, uq, su, ut, nullptr, PS, PZ);
    combine_kernel<<<gB, blk, 0, stream>>>(PS, PZ, V, out, 1, 0);
    for (int it = 1; it < 5; ++it) {
      pass_kernel<1><<<gA, blk, 0, stream>>>(nullptr, Wq, nullptr, nullptr, SWp, uq, su, ut, V, PS, PZ);
      combine_kernel<<<gB, blk, 0, stream>>>(PS, PZ, V, out, 0, it == 4 ? 1 : 0);
    }
  } else {
    pass_kernel<2><<<gA, blk, 0, stream>>>(Wf, nullptr, nullptr, nullptr, nullptr, uq, su, ut, nullptr, PS, PZ);
    combine_kernel<<<gB, blk, 0, stream>>>(PS, PZ, V, out, 1, 0);
    for (int it = 1; it < 5; ++it) {
      pass_kernel<3><<<gA, blk, 0, stream>>>(Wf, nullptr, nullptr, nullptr, nullptr, uq, su, ut, V, PS, PZ);
      combine_kernel<<<gB, blk, 0, stream>>>(PS, PZ, V, out, 0, it == 4 ? 1 : 0);
    }
  }
}

// Round 3
// 512.178 us; speedup vs baseline: 1.0033x; 1.0033x over previous
//
#include <hip/hip_runtime.h>
#include <hip/hip_bf16.h>

#define B_ 32
#define N_ 2048
#define D_ 16
#define J_ 64
#define C_ 32
#define NCHUNK 32
#define ICHUNK 64          // N_/NCHUNK
#define IPW    16          // ICHUNK/4 waves

typedef __attribute__((ext_vector_type(8)))  short short8;
typedef __attribute__((ext_vector_type(4)))  short s16x4;
typedef __attribute__((ext_vector_type(16))) float f32x16;
typedef __attribute__((ext_vector_type(4)))  float f32x4;
typedef __attribute__((ext_vector_type(16))) int   i32x16;
typedef __attribute__((ext_vector_type(2)))  long  longx2;

using bf16_t = __hip_bfloat16;

// ---------------------------------------------------------------------------
// Prep: u (B,N,D) fp32 -> ut (N,B,D) bf16 (fallback path) + uq (N,B,D) int8
// with per-row scale su[i,b] = rowmax/127. One thread per (i,b) row of 16.
// ---------------------------------------------------------------------------
__global__ __launch_bounds__(256) void prep_u_kernel(const float* __restrict__ x,
                                                     bf16_t* __restrict__ ut,
                                                     signed char* __restrict__ uq,
                                                     float* __restrict__ su) {
  int t = blockIdx.x * 256 + threadIdx.x;   // t = i*32 + b
  int b = t & 31;
  int i = t >> 5;
  const float* xp = x + (size_t)(b * N_ + i) * D_;
  float v[16];
  *(f32x4*)(v)      = *(const f32x4*)(xp);
  *(f32x4*)(v + 4)  = *(const f32x4*)(xp + 4);
  *(f32x4*)(v + 8)  = *(const f32x4*)(xp + 8);
  *(f32x4*)(v + 12) = *(const f32x4*)(xp + 12);

  float m = 0.f;
#pragma unroll
  for (int k = 0; k < 16; ++k) m = fmaxf(m, fabsf(v[k]));
  m = fmaxf(m, 1e-20f);
  float inv = 127.0f / m;
  union { longx2 l2; signed char c[16]; } pk;
#pragma unroll
  for (int k = 0; k < 16; ++k) pk.c[k] = (signed char)__float2int_rn(v[k] * inv);
  *(longx2*)(uq + (size_t)t * D_) = pk.l2;
  su[t] = m * (1.0f / 127.0f);

  union { short8 s; bf16_t h[8]; } o0, o1;
#pragma unroll
  for (int k = 0; k < 8; ++k) { o0.h[k] = __float2bfloat16(v[k]); o1.h[k] = __float2bfloat16(v[8 + k]); }
  *(short8*)(ut + (size_t)t * D_)     = o0.s;
  *(short8*)(ut + (size_t)t * D_ + 8) = o1.s;
}

// ---------------------------------------------------------------------------
// Prep W: fp32 (N,J,C,D) -> int8 Wq (same layout) + per-tile scale SW[i*J+j].
// One wave per 512-element tile: 2 KB coalesced read, 6-step shfl absmax,
// 512 B coalesced write. Pure streaming, tiny VGPR -> full occupancy.
// Quantized byte position == element position (identity), matching the
// frag_off addressing in pass_kernel exactly.
// ---------------------------------------------------------------------------
__global__ __launch_bounds__(256) void prep_w_kernel(const float* __restrict__ Wf,
                                                     signed char* __restrict__ Wq,
                                                     float* __restrict__ SW) {
  const int lane = threadIdx.x & 63;
  const int wid  = (blockIdx.x * 256 + threadIdx.x) >> 6;
  const int nw   = gridDim.x * 4;
  for (int tile = wid; tile < N_ * J_; tile += nw) {
    const float* wp = Wf + (size_t)tile * (C_ * D_) + lane * 8;
    f32x4 a = *(const f32x4*)wp;
    f32x4 b = *(const f32x4*)(wp + 4);
    float wv[8] = {a.x, a.y, a.z, a.w, b.x, b.y, b.z, b.w};
    float m = 0.f;
#pragma unroll
    for (int k = 0; k < 8; ++k) m = fmaxf(m, fabsf(wv[k]));
    m = fmaxf(m, __shfl_xor(m, 1));
    m = fmaxf(m, __shfl_xor(m, 2));
    m = fmaxf(m, __shfl_xor(m, 4));
    m = fmaxf(m, __shfl_xor(m, 8));
    m = fmaxf(m, __shfl_xor(m, 16));
    m = fmaxf(m, __shfl_xor(m, 32));
    m = fmaxf(m, 1e-20f);
    float qs = 127.0f / m;
    union { long l; signed char c[8]; } pk;
#pragma unroll
    for (int k = 0; k < 8; ++k) pk.c[k] = (signed char)__float2int_rn(wv[k] * qs);
    *(long*)(Wq + (size_t)tile * (C_ * D_) + lane * 8) = pk.l;
    if (lane == 0) SW[tile] = m * (1.0f / 127.0f);
  }
}

// ---------------------------------------------------------------------------
// Routing pass. One block = (j, i-chunk of 64), 4 waves, 1 wave = 16 i's.
// SWAPPED OPERANDS: mfma(wfrag, ufrag) -> acc[m=c][n=b]:
//   col b = lane&31, row c = (r&3) + 4*(lane>>5) + 8*(r>>2)
// A/B frags share the (free,k) lane layout, so any consistent HW k-mapping
// pairs W[c,d] with u[b,d] correctly.
// int8 dequant: u_hat = (sw[i,j]*su[i,b]) * acc; b=lc so s is a per-lane
// scalar and folds into the logit dot (ph*=s) and S update (es=e*s).
// t-loop is explicitly 2-stage software-pipelined: t+1 loads issue before
// t's MFMA+dequant so L2/L3 latency hides under compute.
// MODE 0: int8 W, uniform weights (iter 0, big ws)
// MODE 1: int8 W, V-based logits (iters 1-4, big ws)
// MODE 2: fp32 W in, uniform, bf16 mfma (fallback iter 0)
// MODE 3: fp32 W in, V-based logits, bf16 mfma (fallback)
// ---------------------------------------------------------------------------
template<int MODE>
__global__ __launch_bounds__(256) void pass_kernel(
    const float*        __restrict__ Wf,
    const signed char*  __restrict__ Wq,
    const float*        __restrict__ SW,
    const signed char*  __restrict__ uq,
    const float*        __restrict__ su,
    const bf16_t*       __restrict__ ut,
    const float*        __restrict__ V,
    float*              __restrict__ PS,
    float*              __restrict__ PZ)
{
  constexpr bool UNIFORM = (MODE == 0 || MODE == 2);
  constexpr bool INT8    = (MODE == 0 || MODE == 1);

  const int tid  = threadIdx.x;
  const int w    = tid >> 6;
  const int lane = tid & 63;
  const int half = lane >> 5;
  const int lc   = lane & 31;          // = b ; also A-frag m / B-frag n

  const int j  = blockIdx.x / NCHUNK;
  const int ch = blockIdx.x % NCHUNK;

  // C/D row (= c) per accumulator reg (measured m74/m101; dtype-independent)
  int crow[16];
#pragma unroll
  for (int r = 0; r < 16; ++r) crow[r] = (r & 3) + 4 * half + 8 * (r >> 2);

  float Vreg[16];
  if (!UNIFORM) {
#pragma unroll
    for (int r = 0; r < 16; ++r) Vreg[r] = V[(lc * J_ + j) * C_ + crow[r]];
  }

  float S[16];
#pragma unroll
  for (int r = 0; r < 16; ++r) S[r] = 0.f;
  float zacc = 0.f;

  const int ibase = ch * ICHUNK + w * IPW;
  const int frag_off = lc * D_ + half * 8;   // element (=byte for i8) offset in 32x16 tile

  if constexpr (INT8) {
    const i32x16 zi = {0,0,0,0,0,0,0,0,0,0,0,0,0,0,0,0};
    // pipeline prologue: t = 0 loads
    long wl = *(const long*)(Wq + ((size_t)ibase * J_ + j) * (C_ * D_) + frag_off);
    long ul = *(const long*)(uq + (size_t)ibase * (B_ * D_) + frag_off);
    float sc = SW[(size_t)ibase * J_ + j] * su[ibase * B_ + lc];

    for (int t = 0; t < IPW; ++t) {
      const int tn = (t + 1 < IPW) ? t + 1 : t;   // clamped prefetch index
      const int in_ = ibase + tn;
      long wl_n = *(const long*)(Wq + ((size_t)in_ * J_ + j) * (C_ * D_) + frag_off);
      long ul_n = *(const long*)(uq + (size_t)in_ * (B_ * D_) + frag_off);
      float sc_n = SW[(size_t)in_ * J_ + j] * su[in_ * B_ + lc];

      i32x16 iacc = __builtin_amdgcn_mfma_i32_32x32x16_i8(wl, ul, zi, 0, 0, 0);

      if constexpr (UNIFORM) {
#pragma unroll
        for (int r = 0; r < 16; ++r) S[r] = fmaf(sc, (float)iacc[r], S[r]);
      } else {
        float af[16];
        float ph = 0.f;
#pragma unroll
        for (int r = 0; r < 16; ++r) { af[r] = (float)iacc[r]; ph = fmaf(Vreg[r], af[r], ph); }
        ph *= sc;                            // dequant the half-dot
        ph += __shfl_xor(ph, 32);            // combine the two half-row sets
        float e = __expf(ph);                // logits are O(0.5); max-free safe
        zacc += e;
        float es = e * sc;
#pragma unroll
        for (int r = 0; r < 16; ++r) S[r] = fmaf(es, af[r], S[r]);
      }
      wl = wl_n; ul = ul_n; sc = sc_n;
    }
  } else {
    const f32x16 zeroacc = {0,0,0,0,0,0,0,0,0,0,0,0,0,0,0,0};
    for (int t = 0; t < IPW; ++t) {
      const int i = ibase + t;
      short8 ufrag = *(const short8*)(ut + (size_t)i * (B_ * D_) + frag_off);
      const size_t tile = ((size_t)i * J_ + j) * (C_ * D_);
      const float* wp = Wf + tile + frag_off;
      f32x4 w0 = *(const f32x4*)(wp);
      f32x4 w1 = *(const f32x4*)(wp + 4);
      union { short8 v; bf16_t h[8]; } cv;
      cv.h[0] = __float2bfloat16(w0.x);
      cv.h[1] = __float2bfloat16(w0.y);
      cv.h[2] = __float2bfloat16(w0.z);
      cv.h[3] = __float2bfloat16(w0.w);
      cv.h[4] = __float2bfloat16(w1.x);
      cv.h[5] = __float2bfloat16(w1.y);
      cv.h[6] = __float2bfloat16(w1.z);
      cv.h[7] = __float2bfloat16(w1.w);
      short8 wfrag = cv.v;

      f32x16 acc = __builtin_amdgcn_mfma_f32_32x32x16_bf16(wfrag, ufrag, zeroacc, 0, 0, 0);

      if constexpr (UNIFORM) {
#pragma unroll
        for (int r = 0; r < 16; ++r) S[r] += acc[r];
      } else {
        float ph = 0.f;
#pragma unroll
        for (int r = 0; r < 16; ++r) ph = fmaf(Vreg[r], acc[r], ph);
        ph += __shfl_xor(ph, 32);
        float e = __expf(ph);
        zacc += e;
#pragma unroll
        for (int r = 0; r < 16; ++r) S[r] = fmaf(e, acc[r], S[r]);
      }
    }
  }

  // Epilogue: transpose [c][b] -> [b][c] through padded LDS (stride 33:
  // bank = (lc + crow) % 32, conflict-free), then coalesced PS writes.
  __shared__ float S_lds[4 * 32 * 33];
  __shared__ float Z_lds[4 * 32];
#pragma unroll
  for (int r = 0; r < 16; ++r)
    S_lds[w * 1056 + lc * 33 + crow[r]] = S[r];
  if (!half)
    Z_lds[w * 32 + lc] = UNIFORM ? (float)IPW : zacc;
  __syncthreads();

  const size_t pbase = (size_t)blockIdx.x * 1024;
  for (int e = tid; e < 1024; e += 256) {
    int b = e >> 5, c = e & 31;
    PS[pbase + e] = S_lds[b * 33 + c] + S_lds[1056 + b * 33 + c] +
                    S_lds[2112 + b * 33 + c] + S_lds[3168 + b * 33 + c];
  }
  if (tid < 32)
    PZ[(size_t)blockIdx.x * 32 + tid] =
        Z_lds[tid] + Z_lds[32 + tid] + Z_lds[64 + tid] + Z_lds[96 + tid];
}

// ---------------------------------------------------------------------------
// Combine chunks -> s, squash -> v, V += v, final iter writes output.
// ---------------------------------------------------------------------------
__global__ __launch_bounds__(256) void combine_kernel(
    const float* __restrict__ PS, const float* __restrict__ PZ,
    float* __restrict__ V, float* __restrict__ out, int first, int last)
{
  int t  = blockIdx.x * 256 + threadIdx.x;  // ((b*J + j)*32 + c)
  int c  = t & 31;
  int bj = t >> 5;
  int b  = bj >> 6;
  int j  = bj & 63;
  float s = 0.f, zz = 0.f;
#pragma unroll
  for (int ch = 0; ch < NCHUNK; ++ch) {
    s  += PS[(size_t)(j * NCHUNK + ch) * 1024 + b * 32 + c];
    zz += PZ[(j * NCHUNK + ch) * 32 + b];
  }
  float sv = s / zz + 1e-7f;                // squash adds eps per-component
  float n = sv * sv;
  n += __shfl_xor(n, 1);
  n += __shfl_xor(n, 2);
  n += __shfl_xor(n, 4);
  n += __shfl_xor(n, 8);
  n += __shfl_xor(n, 16);
  float f = n / ((1.f + n) * sqrtf(n));
  float v = sv * f;
  float Vn = first ? v : (V[t] + v);
  V[t] = Vn;
  if (last) out[t] = v;
}

extern "C" void kernel_launch(void* const* d_in, const int* in_sizes, int n_in,
                              void* d_out, int out_size, void* d_ws, size_t ws_size,
                              hipStream_t stream)
{
  const float* x  = (const float*)d_in[0];
  const float* Wf = (const float*)d_in[1];
  float* out = (float*)d_out;
  char* ws = (char*)d_ws;

  const size_t SZ_WQ = (size_t)N_ * J_ * C_ * D_;          // 64 MB int8 W cache
  const size_t SZ_SW = (size_t)N_ * J_ * 4;                // 512 KB W tile scales
  const size_t SZ_UQ = (size_t)N_ * B_ * D_;               // 1 MB int8 u
  const size_t SZ_SU = (size_t)N_ * B_ * 4;                // 256 KB u row scales
  const size_t SZ_UT = (size_t)N_ * B_ * D_ * 2;           // 2 MB bf16 u (fallback)
  const size_t SZ_V  = (size_t)B_ * J_ * C_ * 4;           // 256 KB
  const size_t SZ_PS = (size_t)J_ * NCHUNK * B_ * C_ * 4;  // 8 MB
  const size_t SZ_PZ = (size_t)J_ * NCHUNK * B_ * 4;       // 256 KB

  const bool big = ws_size >= SZ_WQ + SZ_SW + SZ_UQ + SZ_SU + SZ_UT + SZ_V + SZ_PS + SZ_PZ;
  char* p = ws;
  signed char* Wq = nullptr;
  float* SWp = nullptr;
  if (big) {
    Wq  = (signed char*)p; p += SZ_WQ;
    SWp = (float*)p;       p += SZ_SW;
  }
  signed char* uq = (signed char*)p; p += SZ_UQ;
  float* su = (float*)p;             p += SZ_SU;
  bf16_t* ut = (bf16_t*)p;           p += SZ_UT;
  float*  V  = (float*)p;            p += SZ_V;
  float*  PS = (float*)p;            p += SZ_PS;
  float*  PZ = (float*)p;

  prep_u_kernel<<<dim3((N_ * B_) / 256), dim3(256), 0, stream>>>(x, ut, uq, su);

  dim3 gA(J_ * NCHUNK), blk(256), gB((B_ * J_ * C_) / 256);
  if (big) {
    prep_w_kernel<<<dim3(2048), blk, 0, stream>>>(Wf, Wq, SWp);
    pass_kernel<0><<<gA, blk, 0, stream>>>(nullptr, Wq, SWp, uq, su, nullptr, nullptr, PS, PZ);
    combine_kernel<<<gB, blk, 0, stream>>>(PS, PZ, V, out, 1, 0);
    for (int it = 1; it < 5; ++it) {
      pass_kernel<1><<<gA, blk, 0, stream>>>(nullptr, Wq, SWp, uq, su, nullptr, V, PS, PZ);
      combine_kernel<<<gB, blk, 0, stream>>>(PS, PZ, V, out, 0, it == 4 ? 1 : 0);
    }
  } else {
    pass_kernel<2><<<gA, blk, 0, stream>>>(Wf, nullptr, nullptr, uq, su, ut, nullptr, PS, PZ);
    combine_kernel<<<gB, blk, 0, stream>>>(PS, PZ, V, out, 1, 0);
    for (int it = 1; it < 5; ++it) {
      pass_kernel<3><<<gA, blk, 0, stream>>>(Wf, nullptr, nullptr, uq, su, ut, V, PS, PZ);
      combine_kernel<<<gB, blk, 0, stream>>>(PS, PZ, V, out, 0, it == 4 ? 1 : 0);
    }
  }
}